// Round 3
// baseline (16738.632 us; speedup 1.0000x reference)
//
#include <hip/hip_runtime.h>
#include <hip/hip_fp16.h>

#define BB 64
#define TT 2048
#define DD 256
#define HH 256
#define NCB 16      // column-blocks: each owns 16 h-dims (64 gate cols)
#define NBG 16      // batch-groups: each owns 4 batches
#define BPG 4
#define NTHR 768
#define RSTRIDE 272 // padded row stride (f16) to break LDS bank conflicts

typedef _Float16 h2t   __attribute__((ext_vector_type(2)));
typedef _Float16 f16x4 __attribute__((ext_vector_type(4)));
typedef _Float16 f16x8 __attribute__((ext_vector_type(8)));
union V8 { f16x8 v; h2t p[4]; };
union HU { _Float16 h; unsigned short u; };

__device__ __forceinline__ float sigm(float v){ return __builtin_amdgcn_rcpf(1.f+__expf(-v)); }
__device__ __forceinline__ float tanh_f(float v){ float e=__expf(2.f*v); return 1.f-2.f*__builtin_amdgcn_rcpf(e+1.f); }

// zero the h exchange buffer (2 parity x 2 layer x 64 x 128 dwords) + barrier counters
__global__ void init_ws(unsigned int* __restrict__ hbuf, int* __restrict__ ctr){
    int i = blockIdx.x*256 + threadIdx.x;
    if (i < 2*2*BB*(HH/2)) hbuf[i] = 0u;
    if (i < NBG*16)        ctr[i] = 0;
}

__global__ __launch_bounds__(NTHR, 1) void lstm_ws(
    const float* __restrict__ x,
    const float* __restrict__ W_xh, const float* __restrict__ b_xh,
    const float* __restrict__ W_hh, const float* __restrict__ b_hh,
    float* __restrict__ out,
    unsigned int* __restrict__ hbuf,   // [2 parity][2 layer][64 batch][128 dw] (f16 pairs)
    int* __restrict__ ctr)             // [NBG][16] (64B-spaced counters)
{
    __shared__ _Float16 Wlds[2*64*256];        // [type][col 64][k 256], XOR-swizzled
    __shared__ _Float16 rows[12*RSTRIDE];      // rows 0-3: x, 4-7: h0, 8-11: h1
    __shared__ float    g_lds[12*64];          // dot results [row][col_local]

    const int tid = threadIdx.x;
    const int bid = blockIdx.x;
    const int cb  = bid >> 4;    // col-block 0..15 (owns h-dims [cb*16, cb*16+16))
    const int bg  = bid & 15;    // batch-group 0..15
    const int b0  = bg * BPG;

    // ---- one-time: weights f32 -> f16 into LDS, XOR-swizzled per col ----
    for (int i = tid; i < 2*256*64; i += NTHR) {
        int ty  = i >> 14;            // 0 = W_xh, 1 = W_hh
        int rem = i & 16383;
        int k   = rem >> 6;           // 0..255
        int col = rem & 63;           // local col: g*16 + d
        int g = col >> 4, d = col & 15;
        const float* W = ty ? W_hh : W_xh;
        float v = W[(size_t)k*1024 + g*256 + cb*16 + d];
        Wlds[ty*16384 + col*256 + ((((k>>3) ^ (col&7)))<<3) + (k&7)] = (_Float16)v;
    }
    for (int i = tid; i < 12*RSTRIDE; i += NTHR) rows[i] = (_Float16)0;

    // biases + c-state for update threads (tid < 128)
    float bx[4] = {0,0,0,0}, bh[4] = {0,0,0,0};
    float c_st = 0.f;
    int u_bl = 0, u_l = 0, u_d = 0;
    if (tid < 128) {
        u_bl = tid >> 5; u_l = (tid >> 4) & 1; u_d = tid & 15;
        for (int g = 0; g < 4; ++g) {
            bx[g] = b_xh[g*256 + cb*16 + u_d];
            bh[g] = b_hh[g*256 + cb*16 + u_d];
        }
    }
    __syncthreads();

    // x(0) into rows 0..3
    if (tid >= 512) {
        int t2 = tid - 512, bl = t2 >> 6, kq = t2 & 63;
        float4 v = *(const float4*)&x[((size_t)(b0+bl)*TT + 0)*DD + kq*4];
        f16x4 h; h[0]=(_Float16)v.x; h[1]=(_Float16)v.y; h[2]=(_Float16)v.z; h[3]=(_Float16)v.w;
        *(f16x4*)&rows[bl*RSTRIDE + kq*4] = h;
    }
    __syncthreads();

    // dot-wave mapping
    const int w    = tid >> 6;       // 0..11
    const int lane = tid & 63;
    const int rt   = w >> 2;         // 0=x, 1=h0, 2=h1
    const int cg   = w & 3;
    const int rl   = lane >> 4;      // batch-local
    const int cl   = lane & 15;
    const int col  = cg*16 + cl;
    const int row  = rt*4 + rl;
    const int xw   = col & 7;
    const _Float16* wbase = &Wlds[(rt ? 1 : 0)*16384 + col*256];
    const _Float16* rbase = &rows[row*RSTRIDE];
    int* const myctr = &ctr[bg*16];

    for (int p = 0; p <= TT; ++p) {
        // prefetch x(p+1) into registers (waves 8..11, overlapped with dots)
        float4 xv = {0.f,0.f,0.f,0.f};
        if (tid >= 512 && p + 1 < TT) {
            int t2 = tid - 512, bl = t2 >> 6, kq = t2 & 63;
            xv = *(const float4*)&x[((size_t)(b0+bl)*TT + (p+1))*DD + kq*4];
        }

        // dots: (row, col) over k=256
        float a0=0.f, a1=0.f, a2=0.f, a3=0.f;
#pragma unroll
        for (int kk = 0; kk < 32; ++kk) {
            V8 wv, hv;
            wv.v = *(const f16x8*)&wbase[(kk ^ xw) << 3];
            hv.v = *(const f16x8*)&rbase[kk << 3];
            a0 = __builtin_amdgcn_fdot2(hv.p[0], wv.p[0], a0, false);
            a1 = __builtin_amdgcn_fdot2(hv.p[1], wv.p[1], a1, false);
            a2 = __builtin_amdgcn_fdot2(hv.p[2], wv.p[2], a2, false);
            a3 = __builtin_amdgcn_fdot2(hv.p[3], wv.p[3], a3, false);
        }
        g_lds[row*64 + col] = a0 + a1 + a2 + a3;
        __syncthreads();   // S1: dots done (rows free to overwrite)

        // update (tid<128): layer0 step p, layer1 step p-1
        if (tid < 128) {
            const bool active = u_l ? (p >= 1) : (p < TT);
            float hn = 0.f, cn = c_st;
            if (active) {
                float gi, gf, gg, go;
                if (u_l == 0) {
                    gi = g_lds[(0+u_bl)*64 + 0*16+u_d] + g_lds[(4+u_bl)*64 + 0*16+u_d] + bx[0] + bh[0];
                    gf = g_lds[(0+u_bl)*64 + 1*16+u_d] + g_lds[(4+u_bl)*64 + 1*16+u_d] + bx[1] + bh[1];
                    gg = g_lds[(0+u_bl)*64 + 2*16+u_d] + g_lds[(4+u_bl)*64 + 2*16+u_d] + bx[2] + bh[2];
                    go = g_lds[(0+u_bl)*64 + 3*16+u_d] + g_lds[(4+u_bl)*64 + 3*16+u_d] + bx[3] + bh[3];
                } else {
                    gi = g_lds[(4+u_bl)*64 + 0*16+u_d] + g_lds[(8+u_bl)*64 + 0*16+u_d] + 2.f*bh[0];
                    gf = g_lds[(4+u_bl)*64 + 1*16+u_d] + g_lds[(8+u_bl)*64 + 1*16+u_d] + 2.f*bh[1];
                    gg = g_lds[(4+u_bl)*64 + 2*16+u_d] + g_lds[(8+u_bl)*64 + 2*16+u_d] + 2.f*bh[2];
                    go = g_lds[(4+u_bl)*64 + 3*16+u_d] + g_lds[(8+u_bl)*64 + 3*16+u_d] + 2.f*bh[3];
                }
                cn = c_st*sigm(gf) + sigm(gi)*tanh_f(gg);
                hn = sigm(go)*tanh_f(cn);
                c_st = cn;
                if (u_l) out[((size_t)(b0+u_bl)*TT + (p-1))*HH + cb*16 + u_d] = hn;
            }
            // pack pair -> agent-scope atomic store (coherence-point visibility)
            float hn_hi = __shfl_xor(hn, 1);
            if (active && p < TT && !(u_d & 1)) {
                HU lo, hi; lo.h = (_Float16)hn; hi.h = (_Float16)hn_hi;
                unsigned int uu = (unsigned int)lo.u | ((unsigned int)hi.u << 16);
                __hip_atomic_store(&hbuf[((p&1)*2 + u_l)*8192 + (b0+u_bl)*128 + cb*8 + (u_d>>1)],
                                   uu, __ATOMIC_RELAXED, __HIP_MEMORY_SCOPE_AGENT);
            }
            // final states
            if (active) {
                const size_t FIN = (size_t)BB*TT*HH;
                if (u_l == 0 && p == TT-1) {
                    out[FIN +           (b0+u_bl)*256 + cb*16 + u_d] = hn;
                    out[FIN + 32768 +   (b0+u_bl)*256 + cb*16 + u_d] = cn;
                }
                if (u_l == 1 && p == TT) {
                    out[FIN + 16384 +         (b0+u_bl)*256 + cb*16 + u_d] = hn;
                    out[FIN + 32768 + 16384 + (b0+u_bl)*256 + cb*16 + u_d] = cn;
                }
            }
        }
        // stage x(p+1) into rows 0..3 (dots of phase p finished at S1)
        if (tid >= 512 && p + 1 < TT) {
            int t2 = tid - 512, bl = t2 >> 6, kq = t2 & 63;
            f16x4 h; h[0]=(_Float16)xv.x; h[1]=(_Float16)xv.y; h[2]=(_Float16)xv.z; h[3]=(_Float16)xv.w;
            *(f16x4*)&rows[bl*RSTRIDE + kq*4] = h;
        }

        if (p == TT) break;   // last phase: no exchange needed

        __syncthreads();       // S2: all hbuf stores issued & drained (vmcnt0 at barrier)
        if (tid == 0) {
            __hip_atomic_fetch_add(myctr, 1, __ATOMIC_RELEASE, __HIP_MEMORY_SCOPE_AGENT);
            const int target = NCB * (p + 1);
            while (__hip_atomic_load(myctr, __ATOMIC_ACQUIRE, __HIP_MEMORY_SCOPE_AGENT) < target) {}
        }
        __syncthreads();       // S3: barrier passed

        // gather full h0(p), h1(p-1) -> rows 4..11 (atomic loads bypass L1)
        for (int task = tid; task < 1024; task += NTHR) {
            int r8 = task >> 7, dw = task & 127;
            int l = r8 >> 2, bl = r8 & 3;
            unsigned int uu = __hip_atomic_load(&hbuf[((p&1)*2 + l)*8192 + (b0+bl)*128 + dw],
                                                __ATOMIC_RELAXED, __HIP_MEMORY_SCOPE_AGENT);
            HU lo, hi; lo.u = (unsigned short)(uu & 0xffff); hi.u = (unsigned short)(uu >> 16);
            h2t hh; hh[0] = lo.h; hh[1] = hi.h;
            *(h2t*)&rows[(4 + r8)*RSTRIDE + dw*2] = hh;
        }
        __syncthreads();       // S4: rows ready for next phase
    }
}

extern "C" void kernel_launch(void* const* d_in, const int* in_sizes, int n_in,
                              void* d_out, int out_size, void* d_ws, size_t ws_size,
                              hipStream_t stream) {
    const float* x    = (const float*)d_in[0];
    const float* W_xh = (const float*)d_in[1];
    const float* b_xh = (const float*)d_in[2];
    const float* W_hh = (const float*)d_in[3];
    const float* b_hh = (const float*)d_in[4];
    float* out = (float*)d_out;

    unsigned int* hbuf = (unsigned int*)d_ws;                 // 128 KB
    int* ctr = (int*)((char*)d_ws + (256 << 10));             // 1 KB

    init_ws<<<128, 256, 0, stream>>>(hbuf, ctr);
    lstm_ws<<<NCB*NBG, NTHR, 0, stream>>>(x, W_xh, b_xh, W_hh, b_hh, out, hbuf, ctr);
}